// Round 1
// baseline (1553.650 us; speedup 1.0000x reference)
//
#include <hip/hip_runtime.h>
#include <hip/hip_bf16.h>
#include <stdint.h>

// Problem constants
#define NHEAD 8
#define DMODEL 512
#define DVOCAB 32000
#define M_DIM 4096            // B*P
#define K_DIM 4096            // NHEAD*DMODEL
#define N_DIM 32000           // DVOCAB

typedef short bf16x8 __attribute__((ext_vector_type(8)));
typedef float f32x4 __attribute__((ext_vector_type(4)));
typedef unsigned short ushort8 __attribute__((ext_vector_type(8)));

__device__ __forceinline__ unsigned short f2bf(float f) {
    unsigned int u = __builtin_bit_cast(unsigned int, f);
    u = (u + 0x7fffu + ((u >> 16) & 1u)) >> 16;   // RNE (inputs are finite)
    return (unsigned short)u;
}

__device__ __forceinline__ void load16_to_lds(const void* g, void* l) {
    __builtin_amdgcn_global_load_lds(
        (const __attribute__((address_space(1))) unsigned int*)g,
        (__attribute__((address_space(3))) unsigned int*)l, 16, 0, 0);
}

// ---- x [4096][4096] f32 -> bf16, 8 elems/thread ----
__global__ void cvt_x(const float* __restrict__ in, unsigned short* __restrict__ out) {
    long t = (long)blockIdx.x * 256 + threadIdx.x;        // < 2,097,152
    const float4* s = (const float4*)in + t * 2;
    float4 a = s[0], b = s[1];
    ushort8 o;
    o[0] = f2bf(a.x); o[1] = f2bf(a.y); o[2] = f2bf(a.z); o[3] = f2bf(a.w);
    o[4] = f2bf(b.x); o[5] = f2bf(b.y); o[6] = f2bf(b.z); o[7] = f2bf(b.w);
    *(ushort8*)(out + t * 8) = o;
}

// ---- W [H][V][D] f32 -> Wb [V][H*D] bf16 (B^T layout), 8 elems/thread ----
__global__ void cvt_w(const float* __restrict__ in, unsigned short* __restrict__ out) {
    int t = blockIdx.x * 256 + threadIdx.x;               // < 16,384,000
    int d8 = t & 63;                                      // 8-elem chunk along D
    int hv = t >> 6;                                      // < 256,000
    int h = hv / DVOCAB;
    int v = hv - h * DVOCAB;
    const float4* s = (const float4*)(in + (long)hv * DMODEL + d8 * 8);
    float4 a = s[0], b = s[1];
    ushort8 o;
    o[0] = f2bf(a.x); o[1] = f2bf(a.y); o[2] = f2bf(a.z); o[3] = f2bf(a.w);
    o[4] = f2bf(b.x); o[5] = f2bf(b.y); o[6] = f2bf(b.z); o[7] = f2bf(b.w);
    *(ushort8*)(out + (long)v * K_DIM + h * DMODEL + d8 * 8) = o;
}

// ---- bias [H][V] -> bsum [V] ----
__global__ void bias_red(const float* __restrict__ b, float* __restrict__ out) {
    int v = blockIdx.x * 256 + threadIdx.x;
    if (v >= DVOCAB) return;
    float s = 0.f;
    #pragma unroll
    for (int h = 0; h < NHEAD; ++h) s += b[h * DVOCAB + v];
    out[v] = s;
}

// ---- bf16 GEMM: C[M,N] = A[M,K] * Bt[N,K]^T + bias, m97 structure ----
// 128x128 tile, BK=32, 4 waves in 2x2, each wave 64x64 (4x4 frags 16x16x32)
__global__ __launch_bounds__(256) void gemm_bt(
    const unsigned short* __restrict__ A,   // [4096][4096] bf16
    const unsigned short* __restrict__ B,   // [32000][4096] bf16
    const float* __restrict__ bias,         // [32000]
    float* __restrict__ C)                  // [4096][32000] f32
{
    __shared__ unsigned short As[128 * 32];
    __shared__ unsigned short Bs[128 * 32];

    const int tid = threadIdx.x;
    const int bid = blockIdx.x;
    // XCD-bijective swizzle: 8000 blocks % 8 == 0
    const int wg = (bid & 7) * 1000 + (bid >> 3);
    const int mt = wg & 31;            // 32 M-tiles
    const int nt = wg >> 5;            // 250 N-tiles
    const long m0 = (long)mt * 128;
    const long n0 = (long)nt * 128;

    const int wid = tid >> 6, lane = tid & 63;
    const int wr = wid >> 1, wc = wid & 1;     // wave position in 2x2
    const int lr = lane & 15, lk = lane >> 4;  // frag row/col, k-group

    f32x4 acc[4][4];
    #pragma unroll
    for (int i = 0; i < 4; ++i)
        #pragma unroll
        for (int j = 0; j < 4; ++j)
            acc[i][j] = (f32x4){0.f, 0.f, 0.f, 0.f};

    // staging: 512 chunks of 16B per tile, 2 chunks/thread
    const int c0 = tid, c1 = 256 + tid;
    const int rA0 = c0 >> 2, cA0 = (c0 & 3) * 8;
    const int rA1 = c1 >> 2, cA1 = (c1 & 3) * 8;
    const unsigned short* Ab = A + m0 * K_DIM;
    const unsigned short* Bb = B + n0 * K_DIM;

    int aoff[4], boff[4];
    #pragma unroll
    for (int i = 0; i < 4; ++i) aoff[i] = (wr * 64 + i * 16 + lr) * 32 + lk * 8;
    #pragma unroll
    for (int j = 0; j < 4; ++j) boff[j] = (wc * 64 + j * 16 + lr) * 32 + lk * 8;

    for (int k0 = 0; k0 < K_DIM; k0 += 32) {
        __syncthreads();   // previous compute done before overwriting LDS
        load16_to_lds(Ab + (long)rA0 * K_DIM + k0 + cA0, &As[c0 * 8]);
        load16_to_lds(Ab + (long)rA1 * K_DIM + k0 + cA1, &As[c1 * 8]);
        load16_to_lds(Bb + (long)rA0 * K_DIM + k0 + cA0, &Bs[c0 * 8]);
        load16_to_lds(Bb + (long)rA1 * K_DIM + k0 + cA1, &Bs[c1 * 8]);
        __syncthreads();   // compiler drains vmcnt before barrier

        bf16x8 af[4], bfr[4];
        #pragma unroll
        for (int i = 0; i < 4; ++i) af[i] = *(const bf16x8*)(As + aoff[i]);
        #pragma unroll
        for (int j = 0; j < 4; ++j) bfr[j] = *(const bf16x8*)(Bs + boff[j]);
        #pragma unroll
        for (int i = 0; i < 4; ++i)
            #pragma unroll
            for (int j = 0; j < 4; ++j)
                acc[i][j] = __builtin_amdgcn_mfma_f32_16x16x32_bf16(
                    af[i], bfr[j], acc[i][j], 0, 0, 0);
    }

    // epilogue: C/D layout col = lane&15, row = (lane>>4)*4 + reg
    const long crow0 = m0 + wr * 64;
    const long ccol0 = n0 + wc * 64;
    #pragma unroll
    for (int j = 0; j < 4; ++j) {
        const long col = ccol0 + j * 16 + lr;
        const float bs = bias[col];
        #pragma unroll
        for (int i = 0; i < 4; ++i) {
            const long row = crow0 + i * 16 + lk * 4;
            #pragma unroll
            for (int r = 0; r < 4; ++r)
                C[(row + r) * (long)N_DIM + col] = acc[i][j][r] + bs;
        }
    }
}

// ---- emergency fallback if ws too small: naive fp32 (slow but correct) ----
__global__ void naive_out(const float* __restrict__ x, const float* __restrict__ w,
                          const float* __restrict__ b, float* __restrict__ out) {
    long idx = (long)blockIdx.x * 256 + threadIdx.x;
    if (idx >= (long)M_DIM * N_DIM) return;
    long m = idx / N_DIM;
    int v = (int)(idx - m * N_DIM);
    float s = 0.f;
    for (int h = 0; h < NHEAD; ++h) {
        const float* xr = x + m * K_DIM + h * DMODEL;
        const float* wr = w + ((long)h * DVOCAB + v) * DMODEL;
        float ps = 0.f;
        for (int d = 0; d < DMODEL; ++d) ps += xr[d] * wr[d];
        s += ps + b[h * DVOCAB + v];
    }
    out[idx] = s;
}

extern "C" void kernel_launch(void* const* d_in, const int* in_sizes, int n_in,
                              void* d_out, int out_size, void* d_ws, size_t ws_size,
                              hipStream_t stream) {
    const float* x = (const float*)d_in[0];   // [8,512,8,512]
    const float* w = (const float*)d_in[1];   // [8,32000,512]
    const float* b = (const float*)d_in[2];   // [8,32000]
    float* out = (float*)d_out;               // [8,512,32000]

    const size_t xbf_bytes = (size_t)M_DIM * K_DIM * 2;          // 33,554,432
    const size_t wbf_bytes = (size_t)N_DIM * K_DIM * 2;          // 262,144,000
    const size_t bs_bytes  = (size_t)N_DIM * 4;                  // 128,000
    const size_t need = xbf_bytes + wbf_bytes + bs_bytes;

    if (ws_size < need) {
        long total = (long)M_DIM * N_DIM;
        int blocks = (int)((total + 255) / 256);
        naive_out<<<blocks, 256, 0, stream>>>(x, w, b, out);
        return;
    }

    unsigned short* xbf = (unsigned short*)d_ws;
    unsigned short* wbf = (unsigned short*)((char*)d_ws + xbf_bytes);
    float* bsum = (float*)((char*)d_ws + xbf_bytes + wbf_bytes);

    cvt_x<<<8192, 256, 0, stream>>>(x, xbf);                    // 16.78M elems
    cvt_w<<<64000, 256, 0, stream>>>(w, wbf);                   // 131M elems
    bias_red<<<125, 256, 0, stream>>>(b, bsum);
    gemm_bt<<<8000, 256, 0, stream>>>(xbf, wbf, bsum, out);     // 32 x 250 tiles
}

// Round 2
// 1122.867 us; speedup vs baseline: 1.3836x; 1.3836x over previous
//
#include <hip/hip_runtime.h>
#include <hip/hip_bf16.h>
#include <stdint.h>

// Problem constants
#define NHEAD 8
#define DMODEL 512
#define DVOCAB 32000
#define M_DIM 4096            // B*P
#define K_DIM 4096            // NHEAD*DMODEL
#define N_DIM 32000           // DVOCAB
#define NT    64              // K_DIM / 64 k-tiles

typedef short bf16x8 __attribute__((ext_vector_type(8)));
typedef float f32x4 __attribute__((ext_vector_type(4)));
typedef unsigned short ushort8 __attribute__((ext_vector_type(8)));

__device__ __forceinline__ unsigned short f2bf(float f) {
    unsigned int u = __builtin_bit_cast(unsigned int, f);
    u = (u + 0x7fffu + ((u >> 16) & 1u)) >> 16;   // RNE (inputs are finite)
    return (unsigned short)u;
}

__device__ __forceinline__ void load16_to_lds(const void* g, void* l) {
    __builtin_amdgcn_global_load_lds(
        (const __attribute__((address_space(1))) unsigned int*)g,
        (__attribute__((address_space(3))) unsigned int*)l, 16, 0, 0);
}

// ---- x [4096][4096] f32 -> bf16, 8 elems/thread ----
__global__ void cvt_x(const float* __restrict__ in, unsigned short* __restrict__ out) {
    long t = (long)blockIdx.x * 256 + threadIdx.x;
    const float4* s = (const float4*)in + t * 2;
    float4 a = s[0], b = s[1];
    ushort8 o;
    o[0] = f2bf(a.x); o[1] = f2bf(a.y); o[2] = f2bf(a.z); o[3] = f2bf(a.w);
    o[4] = f2bf(b.x); o[5] = f2bf(b.y); o[6] = f2bf(b.z); o[7] = f2bf(b.w);
    *(ushort8*)(out + t * 8) = o;
}

// ---- W [H][V][D] f32 -> Wb [V][H*D] bf16 (B^T layout), 8 elems/thread ----
__global__ void cvt_w(const float* __restrict__ in, unsigned short* __restrict__ out) {
    int t = blockIdx.x * 256 + threadIdx.x;
    int d8 = t & 63;
    int hv = t >> 6;
    int h = hv / DVOCAB;
    int v = hv - h * DVOCAB;
    const float4* s = (const float4*)(in + (long)hv * DMODEL + d8 * 8);
    float4 a = s[0], b = s[1];
    ushort8 o;
    o[0] = f2bf(a.x); o[1] = f2bf(a.y); o[2] = f2bf(a.z); o[3] = f2bf(a.w);
    o[4] = f2bf(b.x); o[5] = f2bf(b.y); o[6] = f2bf(b.z); o[7] = f2bf(b.w);
    *(ushort8*)(out + (long)v * K_DIM + h * DMODEL + d8 * 8) = o;
}

// ---- bias [H][V] -> bsum [V] ----
__global__ void bias_red(const float* __restrict__ b, float* __restrict__ out) {
    int v = blockIdx.x * 256 + threadIdx.x;
    if (v >= DVOCAB) return;
    float s = 0.f;
    #pragma unroll
    for (int h = 0; h < NHEAD; ++h) s += b[h * DVOCAB + v];
    out[v] = s;
}

// LDS fragment read with st-swizzle (chunk ^= row&7), ushort index math
__device__ __forceinline__ bf16x8 fragld(const unsigned short* base, int r, int ks, int lk) {
    return *(const bf16x8*)(base + (r << 6) + (((((ks << 2) | lk)) ^ (r & 7)) << 3));
}

#define BAR()    __builtin_amdgcn_s_barrier()
#define LGKM0()  asm volatile("s_waitcnt lgkmcnt(0)" ::: "memory")
#define VMCNT6() asm volatile("s_waitcnt vmcnt(6)" ::: "memory")
#define VMCNT0() asm volatile("s_waitcnt vmcnt(0)" ::: "memory")

// ---- bf16 GEMM, 256x256 tile, BK=64, 8-phase schedule (m201 template) ----
// C[M,N] = A[M,K] * Bt[N,K]^T + bias
__global__ __launch_bounds__(512, 2) void gemm256(
    const unsigned short* __restrict__ A,   // [4096][4096] bf16
    const unsigned short* __restrict__ B,   // [32000][4096] bf16
    const float* __restrict__ bias,         // [32000]
    float* __restrict__ C)                  // [4096][32000] f32
{
    // [buf][op A=0/B=1][half][128*64 elems], 128 KiB total
    __shared__ __attribute__((aligned(16))) unsigned short lds[2][2][2][8192];

    const int tid = threadIdx.x;
    const int bid = blockIdx.x;
    // XCD-bijective swizzle: 2000 blocks, 8 XCDs, 250 per XCD
    const int wg = (bid & 7) * 250 + (bid >> 3);
    const int mt = wg & 15;            // 16 M-tiles
    const int nt = wg >> 4;            // 125 N-tiles
    const long m0 = (long)mt * 256;
    const long n0 = (long)nt * 256;

    const int wid = tid >> 6, lane = tid & 63;
    const int wr = wid >> 2, wc = wid & 3;     // 2 x 4 waves
    const int lr = lane & 15, lk = lane >> 4;

    // staging per-thread offsets (2 x 16B per half-tile)
    const int row0 = tid >> 3,         ch0 = (tid & 7) ^ (row0 & 7);
    const int row1 = (512 + tid) >> 3, ch1 = ((512 + tid) & 7) ^ (row1 & 7);
    const unsigned short* Ab = A + m0 * K_DIM;
    const unsigned short* Bb = B + n0 * K_DIM;

    // stage half-tile: OP in {0=A,1=B}, HALF in {0,1}, tile T -> buf T&1
    #define STAGE(T, OP, HALF) do {                                             \
        const unsigned short* _gb = ((OP) ? Bb : Ab)                            \
            + (size_t)((HALF) * 128) * K_DIM + (size_t)(T) * 64;                \
        unsigned short* _lb = &lds[(T) & 1][OP][HALF][0];                       \
        load16_to_lds(_gb + (size_t)row0 * K_DIM + ch0 * 8, _lb + tid * 8);     \
        load16_to_lds(_gb + (size_t)row1 * K_DIM + ch1 * 8, _lb + (512 + tid) * 8); \
    } while (0)

    f32x4 acc[8][4];
    #pragma unroll
    for (int i = 0; i < 8; ++i)
        #pragma unroll
        for (int j = 0; j < 4; ++j)
            acc[i][j] = (f32x4){0.f, 0.f, 0.f, 0.f};

    // prologue: tile0 fully + tile1 h0..h2; keep 6 loads in flight
    STAGE(0, 0, 0); STAGE(0, 1, 0); STAGE(0, 1, 1); STAGE(0, 0, 1);
    STAGE(1, 0, 0); STAGE(1, 1, 0); STAGE(1, 1, 1);
    VMCNT6();
    BAR();

    bf16x8 af[4][2], bf0[2][2], bf1[2][2];

    for (int t = 0; t < NT; ++t) {
        const int cur = t & 1;
        const unsigned short* Ah0p = &lds[cur][0][0][0];
        const unsigned short* Ah1p = &lds[cur][0][1][0];
        const unsigned short* Bh0p = &lds[cur][1][0][0];
        const unsigned short* Bh1p = &lds[cur][1][1][0];

        // ---- P1: read A-half0 + B-half0, stage (t+1).Ah1, MFMA quad(0,0)
        #pragma unroll
        for (int mi = 0; mi < 4; ++mi) {
            int r = wr * 64 + mi * 16 + lr;
            af[mi][0] = fragld(Ah0p, r, 0, lk);
            af[mi][1] = fragld(Ah0p, r, 1, lk);
        }
        #pragma unroll
        for (int nj = 0; nj < 2; ++nj) {
            int r = wc * 32 + nj * 16 + lr;
            bf0[nj][0] = fragld(Bh0p, r, 0, lk);
            bf0[nj][1] = fragld(Bh0p, r, 1, lk);
        }
        if (t + 1 < NT) STAGE(t + 1, 0, 1);
        BAR(); LGKM0();
        __builtin_amdgcn_s_setprio(1);
        #pragma unroll
        for (int mi = 0; mi < 4; ++mi)
            #pragma unroll
            for (int nj = 0; nj < 2; ++nj)
                #pragma unroll
                for (int ks = 0; ks < 2; ++ks)
                    acc[mi][nj] = __builtin_amdgcn_mfma_f32_16x16x32_bf16(
                        af[mi][ks], bf0[nj][ks], acc[mi][nj], 0, 0, 0);
        __builtin_amdgcn_s_setprio(0);
        BAR();

        // ---- P2: read B-half1, stage (t+2).Ah0, MFMA quad(0,1)
        #pragma unroll
        for (int nj = 0; nj < 2; ++nj) {
            int r = wc * 32 + nj * 16 + lr;
            bf1[nj][0] = fragld(Bh1p, r, 0, lk);
            bf1[nj][1] = fragld(Bh1p, r, 1, lk);
        }
        if (t + 2 < NT) STAGE(t + 2, 0, 0);
        BAR(); LGKM0();
        __builtin_amdgcn_s_setprio(1);
        #pragma unroll
        for (int mi = 0; mi < 4; ++mi)
            #pragma unroll
            for (int nj = 0; nj < 2; ++nj)
                #pragma unroll
                for (int ks = 0; ks < 2; ++ks)
                    acc[mi][2 + nj] = __builtin_amdgcn_mfma_f32_16x16x32_bf16(
                        af[mi][ks], bf1[nj][ks], acc[mi][2 + nj], 0, 0, 0);
        __builtin_amdgcn_s_setprio(0);
        BAR();

        // ---- P3: read A-half1, stage (t+2).Bh0, MFMA quad(1,0)
        #pragma unroll
        for (int mi = 0; mi < 4; ++mi) {
            int r = wr * 64 + mi * 16 + lr;
            af[mi][0] = fragld(Ah1p, r, 0, lk);
            af[mi][1] = fragld(Ah1p, r, 1, lk);
        }
        if (t + 2 < NT) STAGE(t + 2, 1, 0);
        BAR(); LGKM0();
        __builtin_amdgcn_s_setprio(1);
        #pragma unroll
        for (int mi = 0; mi < 4; ++mi)
            #pragma unroll
            for (int nj = 0; nj < 2; ++nj)
                #pragma unroll
                for (int ks = 0; ks < 2; ++ks)
                    acc[4 + mi][nj] = __builtin_amdgcn_mfma_f32_16x16x32_bf16(
                        af[mi][ks], bf0[nj][ks], acc[4 + mi][nj], 0, 0, 0);
        __builtin_amdgcn_s_setprio(0);
        BAR();

        // ---- P4: stage (t+2).Bh1, counted vmcnt, MFMA quad(1,1)
        if (t + 2 < NT) STAGE(t + 2, 1, 1);
        if (t < NT - 2) { VMCNT6(); } else { VMCNT0(); }
        BAR();
        __builtin_amdgcn_s_setprio(1);
        #pragma unroll
        for (int mi = 0; mi < 4; ++mi)
            #pragma unroll
            for (int nj = 0; nj < 2; ++nj)
                #pragma unroll
                for (int ks = 0; ks < 2; ++ks)
                    acc[4 + mi][2 + nj] = __builtin_amdgcn_mfma_f32_16x16x32_bf16(
                        af[mi][ks], bf1[nj][ks], acc[4 + mi][2 + nj], 0, 0, 0);
        __builtin_amdgcn_s_setprio(0);
        BAR();
    }
    #undef STAGE

    // epilogue: C/D layout col = lane&15 (lr), row = lk*4 + reg
    #pragma unroll
    for (int nj = 0; nj < 4; ++nj) {
        const long col = n0 + (nj >> 1) * 128 + wc * 32 + (nj & 1) * 16 + lr;
        const float bs = bias[col];
        #pragma unroll
        for (int mi = 0; mi < 8; ++mi) {
            const long row = m0 + (mi >> 2) * 128 + wr * 64 + (mi & 3) * 16 + lk * 4;
            #pragma unroll
            for (int r = 0; r < 4; ++r)
                C[(row + r) * (long)N_DIM + col] = acc[mi][nj][r] + bs;
        }
    }
}

// ---- emergency fallback if ws too small: naive fp32 (slow but correct) ----
__global__ void naive_out(const float* __restrict__ x, const float* __restrict__ w,
                          const float* __restrict__ b, float* __restrict__ out) {
    long idx = (long)blockIdx.x * 256 + threadIdx.x;
    if (idx >= (long)M_DIM * N_DIM) return;
    long m = idx / N_DIM;
    int v = (int)(idx - m * N_DIM);
    float s = 0.f;
    for (int h = 0; h < NHEAD; ++h) {
        const float* xr = x + m * K_DIM + h * DMODEL;
        const float* wr = w + ((long)h * DVOCAB + v) * DMODEL;
        float ps = 0.f;
        for (int d = 0; d < DMODEL; ++d) ps += xr[d] * wr[d];
        s += ps + b[h * DVOCAB + v];
    }
    out[idx] = s;
}

extern "C" void kernel_launch(void* const* d_in, const int* in_sizes, int n_in,
                              void* d_out, int out_size, void* d_ws, size_t ws_size,
                              hipStream_t stream) {
    const float* x = (const float*)d_in[0];   // [8,512,8,512]
    const float* w = (const float*)d_in[1];   // [8,32000,512]
    const float* b = (const float*)d_in[2];   // [8,32000]
    float* out = (float*)d_out;               // [8,512,32000]

    const size_t xbf_bytes = (size_t)M_DIM * K_DIM * 2;
    const size_t wbf_bytes = (size_t)N_DIM * K_DIM * 2;
    const size_t bs_bytes  = (size_t)N_DIM * 4;
    const size_t need = xbf_bytes + wbf_bytes + bs_bytes;

    if (ws_size < need) {
        long total = (long)M_DIM * N_DIM;
        int blocks = (int)((total + 255) / 256);
        naive_out<<<blocks, 256, 0, stream>>>(x, w, b, out);
        return;
    }

    unsigned short* xbf = (unsigned short*)d_ws;
    unsigned short* wbf = (unsigned short*)((char*)d_ws + xbf_bytes);
    float* bsum = (float*)((char*)d_ws + xbf_bytes + wbf_bytes);

    cvt_x<<<8192, 256, 0, stream>>>(x, xbf);
    cvt_w<<<64000, 256, 0, stream>>>(w, wbf);
    bias_red<<<125, 256, 0, stream>>>(b, bsum);
    gemm256<<<2000, 512, 0, stream>>>(xbf, wbf, bsum, out);  // 16 x 125 tiles
}

// Round 3
// 1084.756 us; speedup vs baseline: 1.4323x; 1.0351x over previous
//
#include <hip/hip_runtime.h>
#include <hip/hip_bf16.h>
#include <stdint.h>

// Problem constants
#define NHEAD 8
#define DMODEL 512
#define DVOCAB 32000
#define M_DIM 4096            // B*P
#define K_DIM 4096            // NHEAD*DMODEL
#define N_DIM 32000           // DVOCAB
#define NT    64              // K_DIM / 64 k-tiles

typedef short bf16x8 __attribute__((ext_vector_type(8)));
typedef float f32x4 __attribute__((ext_vector_type(4)));
typedef unsigned short ushort8 __attribute__((ext_vector_type(8)));

template <int V> struct IC { static constexpr int v = V; };

__device__ __forceinline__ unsigned short f2bf(float f) {
    unsigned int u = __builtin_bit_cast(unsigned int, f);
    u = (u + 0x7fffu + ((u >> 16) & 1u)) >> 16;   // RNE (inputs are finite)
    return (unsigned short)u;
}

__device__ __forceinline__ void load16_to_lds(const void* g, void* l) {
    __builtin_amdgcn_global_load_lds(
        (const __attribute__((address_space(1))) unsigned int*)g,
        (__attribute__((address_space(3))) unsigned int*)l, 16, 0, 0);
}

// ---- x [4096][4096] f32 -> bf16, 8 elems/thread ----
__global__ void cvt_x(const float* __restrict__ in, unsigned short* __restrict__ out) {
    long t = (long)blockIdx.x * 256 + threadIdx.x;
    const float4* s = (const float4*)in + t * 2;
    float4 a = s[0], b = s[1];
    ushort8 o;
    o[0] = f2bf(a.x); o[1] = f2bf(a.y); o[2] = f2bf(a.z); o[3] = f2bf(a.w);
    o[4] = f2bf(b.x); o[5] = f2bf(b.y); o[6] = f2bf(b.z); o[7] = f2bf(b.w);
    *(ushort8*)(out + t * 8) = o;
}

// ---- W [H][V][D] f32 -> Wb [V][H*D] bf16 (B^T layout), 8 elems/thread ----
__global__ void cvt_w(const float* __restrict__ in, unsigned short* __restrict__ out) {
    int t = blockIdx.x * 256 + threadIdx.x;
    int d8 = t & 63;
    int hv = t >> 6;
    int h = hv / DVOCAB;
    int v = hv - h * DVOCAB;
    const float4* s = (const float4*)(in + (long)hv * DMODEL + d8 * 8);
    float4 a = s[0], b = s[1];
    ushort8 o;
    o[0] = f2bf(a.x); o[1] = f2bf(a.y); o[2] = f2bf(a.z); o[3] = f2bf(a.w);
    o[4] = f2bf(b.x); o[5] = f2bf(b.y); o[6] = f2bf(b.z); o[7] = f2bf(b.w);
    *(ushort8*)(out + (long)v * K_DIM + h * DMODEL + d8 * 8) = o;
}

// ---- bias [H][V] -> bsum [V] ----
__global__ void bias_red(const float* __restrict__ b, float* __restrict__ out) {
    int v = blockIdx.x * 256 + threadIdx.x;
    if (v >= DVOCAB) return;
    float s = 0.f;
    #pragma unroll
    for (int h = 0; h < NHEAD; ++h) s += b[h * DVOCAB + v];
    out[v] = s;
}

#define BAR()    __builtin_amdgcn_s_barrier()
#define LGKM0()  asm volatile("s_waitcnt lgkmcnt(0)" ::: "memory")
#define VMCNT6() asm volatile("s_waitcnt vmcnt(6)" ::: "memory")
#define VMCNT0() asm volatile("s_waitcnt vmcnt(0)" ::: "memory")

// ---- bf16 GEMM, 256x256 tile, BK=64, 8-phase schedule (m201 template) ----
// C[M,N] = A[M,K] * Bt[N,K]^T + bias
// LDS layout [op][half][buf] so all ds_reads are base-VGPR + immediate.
__global__ __launch_bounds__(512, 2) void gemm256(
    const unsigned short* __restrict__ A,   // [4096][4096] bf16
    const unsigned short* __restrict__ B,   // [32000][4096] bf16
    const float* __restrict__ bias,         // [32000]
    float* __restrict__ C)                  // [4096][32000] f32
{
    __shared__ __attribute__((aligned(16))) unsigned short lds[2][2][2][8192];

    const int tid = threadIdx.x;
    const int bid = blockIdx.x;
    // XCD-bijective swizzle: 2000 blocks, 8 XCDs, 250 per XCD
    const int wg = (bid & 7) * 250 + (bid >> 3);
    const int mt = wg & 15;            // 16 M-tiles
    const int nt = wg >> 4;            // 125 N-tiles
    const long m0 = (long)mt * 256;
    const long n0 = (long)nt * 256;

    const int wid = tid >> 6, lane = tid & 63;
    const int wr = wid >> 2, wc = wid & 3;     // 2 x 4 waves
    const int lr = lane & 15, lk = lane >> 4;
    const int swz = lr & 7;                    // row&7 == lr&7 for all frag rows

    // ds_read base pointers: 4 VGPRs, everything else immediate offsets
    const unsigned short* pA[2];
    const unsigned short* pB[2];
    #pragma unroll
    for (int ks = 0; ks < 2; ++ks) {
        const int ch = ((ks << 2) | lk) ^ swz;
        pA[ks] = &lds[0][0][0][0] + (wr * 64 + lr) * 64 + ch * 8;
        pB[ks] = &lds[1][0][0][0] + (wc * 32 + lr) * 64 + ch * 8;
    }
    // frag read: [mi rows of 16][half][buf] as compile-time immediates (<64KiB)
    #define LDA(mi, ks, HALF, CURB) \
        (*(const bf16x8*)(pA[ks] + (mi) * 1024 + (HALF) * 16384 + (CURB) * 8192))
    #define LDB(nj, ks, HALF, CURB) \
        (*(const bf16x8*)(pB[ks] + (nj) * 1024 + (HALF) * 16384 + (CURB) * 8192))

    // staging: per-lane 32-bit byte offsets off uniform bases, advanced +128B/use
    const char* Ab = (const char*)(A + m0 * K_DIM);
    const char* Bb = (const char*)(B + n0 * K_DIM);
    const int row0 = tid >> 3,         c0 = (tid & 7) ^ (row0 & 7);
    const int row1 = (512 + tid) >> 3, c1 = ((512 + tid) & 7) ^ (row1 & 7);
    unsigned int a00 = (unsigned)(row0 * K_DIM + c0 * 8) * 2u;
    unsigned int a01 = (unsigned)(row1 * K_DIM + c1 * 8) * 2u;
    unsigned int a10 = (unsigned)((128 + row0) * K_DIM + c0 * 8) * 2u;
    unsigned int a11 = (unsigned)((128 + row1) * K_DIM + c1 * 8) * 2u;
    unsigned int b00 = a00, b01 = a01, b10 = a10, b11 = a11;

    #define ST_A0(CURB) do { \
        load16_to_lds(Ab + a00, (char*)&lds[0][0][(CURB)][0] + tid * 16); \
        load16_to_lds(Ab + a01, (char*)&lds[0][0][(CURB)][0] + 8192 + tid * 16); \
        a00 += 128; a01 += 128; } while (0)
    #define ST_A1(CURB) do { \
        load16_to_lds(Ab + a10, (char*)&lds[0][1][(CURB)][0] + tid * 16); \
        load16_to_lds(Ab + a11, (char*)&lds[0][1][(CURB)][0] + 8192 + tid * 16); \
        a10 += 128; a11 += 128; } while (0)
    #define ST_B0(CURB) do { \
        load16_to_lds(Bb + b00, (char*)&lds[1][0][(CURB)][0] + tid * 16); \
        load16_to_lds(Bb + b01, (char*)&lds[1][0][(CURB)][0] + 8192 + tid * 16); \
        b00 += 128; b01 += 128; } while (0)
    #define ST_B1(CURB) do { \
        load16_to_lds(Bb + b10, (char*)&lds[1][1][(CURB)][0] + tid * 16); \
        load16_to_lds(Bb + b11, (char*)&lds[1][1][(CURB)][0] + 8192 + tid * 16); \
        b10 += 128; b11 += 128; } while (0)

    f32x4 acc[8][4];
    #pragma unroll
    for (int i = 0; i < 8; ++i)
        #pragma unroll
        for (int j = 0; j < 4; ++j)
            acc[i][j] = (f32x4){0.f, 0.f, 0.f, 0.f};

    bf16x8 af[4][2], bf0[2][2], bf1[2][2];

    // prologue: tile0 fully + tile1 {Ah0,Bh0,Bh1}; 14 loads, keep 6 in flight
    ST_A0(0); ST_B0(0); ST_B1(0); ST_A1(0);
    ST_A0(1); ST_B0(1); ST_B1(1);
    VMCNT6();
    BAR();

    auto body = [&](auto curc, int t) {
        constexpr int CUR = decltype(curc)::v;

        // ---- P1: read A-h0 + B-h0, stage (t+1).Ah1, MFMA quad(0,0)
        #pragma unroll
        for (int mi = 0; mi < 4; ++mi) {
            af[mi][0] = LDA(mi, 0, 0, CUR);
            af[mi][1] = LDA(mi, 1, 0, CUR);
        }
        #pragma unroll
        for (int nj = 0; nj < 2; ++nj) {
            bf0[nj][0] = LDB(nj, 0, 0, CUR);
            bf0[nj][1] = LDB(nj, 1, 0, CUR);
        }
        if (t + 1 < NT) ST_A1(CUR ^ 1);
        BAR(); LGKM0();
        __builtin_amdgcn_s_setprio(1);
        #pragma unroll
        for (int mi = 0; mi < 4; ++mi)
            #pragma unroll
            for (int nj = 0; nj < 2; ++nj)
                #pragma unroll
                for (int ks = 0; ks < 2; ++ks)
                    acc[mi][nj] = __builtin_amdgcn_mfma_f32_16x16x32_bf16(
                        af[mi][ks], bf0[nj][ks], acc[mi][nj], 0, 0, 0);
        __builtin_amdgcn_s_setprio(0);
        BAR();

        // ---- P2: read B-h1, stage (t+2).Ah0, MFMA quad(0,1)
        #pragma unroll
        for (int nj = 0; nj < 2; ++nj) {
            bf1[nj][0] = LDB(nj, 0, 1, CUR);
            bf1[nj][1] = LDB(nj, 1, 1, CUR);
        }
        if (t + 2 < NT) ST_A0(CUR);
        BAR(); LGKM0();
        __builtin_amdgcn_s_setprio(1);
        #pragma unroll
        for (int mi = 0; mi < 4; ++mi)
            #pragma unroll
            for (int nj = 0; nj < 2; ++nj)
                #pragma unroll
                for (int ks = 0; ks < 2; ++ks)
                    acc[mi][2 + nj] = __builtin_amdgcn_mfma_f32_16x16x32_bf16(
                        af[mi][ks], bf1[nj][ks], acc[mi][2 + nj], 0, 0, 0);
        __builtin_amdgcn_s_setprio(0);
        BAR();

        // ---- P3: read A-h1, stage (t+2).Bh0, MFMA quad(1,0)
        #pragma unroll
        for (int mi = 0; mi < 4; ++mi) {
            af[mi][0] = LDA(mi, 0, 1, CUR);
            af[mi][1] = LDA(mi, 1, 1, CUR);
        }
        if (t + 2 < NT) ST_B0(CUR);
        BAR(); LGKM0();
        __builtin_amdgcn_s_setprio(1);
        #pragma unroll
        for (int mi = 0; mi < 4; ++mi)
            #pragma unroll
            for (int nj = 0; nj < 2; ++nj)
                #pragma unroll
                for (int ks = 0; ks < 2; ++ks)
                    acc[4 + mi][nj] = __builtin_amdgcn_mfma_f32_16x16x32_bf16(
                        af[mi][ks], bf0[nj][ks], acc[4 + mi][nj], 0, 0, 0);
        __builtin_amdgcn_s_setprio(0);
        BAR();

        // ---- P4: stage (t+2).Bh1, counted vmcnt, MFMA quad(1,1)
        if (t + 2 < NT) ST_B1(CUR);
        if (t < NT - 2) { VMCNT6(); } else { VMCNT0(); }
        BAR();
        __builtin_amdgcn_s_setprio(1);
        #pragma unroll
        for (int mi = 0; mi < 4; ++mi)
            #pragma unroll
            for (int nj = 0; nj < 2; ++nj)
                #pragma unroll
                for (int ks = 0; ks < 2; ++ks)
                    acc[4 + mi][2 + nj] = __builtin_amdgcn_mfma_f32_16x16x32_bf16(
                        af[mi][ks], bf1[nj][ks], acc[4 + mi][2 + nj], 0, 0, 0);
        __builtin_amdgcn_s_setprio(0);
        BAR();
    };

    for (int t = 0; t < NT; t += 2) {
        body(IC<0>{}, t);
        body(IC<1>{}, t + 1);
    }
    #undef LDA
    #undef LDB
    #undef ST_A0
    #undef ST_A1
    #undef ST_B0
    #undef ST_B1

    // epilogue: C/D layout col = lane&15 (lr), row = lk*4 + reg; nontemporal
    #pragma unroll
    for (int nj = 0; nj < 4; ++nj) {
        const long col = n0 + (nj >> 1) * 128 + wc * 32 + (nj & 1) * 16 + lr;
        const float bs = bias[col];
        #pragma unroll
        for (int mi = 0; mi < 8; ++mi) {
            const long row = m0 + (mi >> 2) * 128 + wr * 64 + (mi & 3) * 16 + lk * 4;
            #pragma unroll
            for (int r = 0; r < 4; ++r)
                __builtin_nontemporal_store(acc[mi][nj][r] + bs,
                                            &C[(row + r) * (long)N_DIM + col]);
        }
    }
}

// ---- emergency fallback if ws too small: naive fp32 (slow but correct) ----
__global__ void naive_out(const float* __restrict__ x, const float* __restrict__ w,
                          const float* __restrict__ b, float* __restrict__ out) {
    long idx = (long)blockIdx.x * 256 + threadIdx.x;
    if (idx >= (long)M_DIM * N_DIM) return;
    long m = idx / N_DIM;
    int v = (int)(idx - m * N_DIM);
    float s = 0.f;
    for (int h = 0; h < NHEAD; ++h) {
        const float* xr = x + m * K_DIM + h * DMODEL;
        const float* wr = w + ((long)h * DVOCAB + v) * DMODEL;
        float ps = 0.f;
        for (int d = 0; d < DMODEL; ++d) ps += xr[d] * wr[d];
        s += ps + b[h * DVOCAB + v];
    }
    out[idx] = s;
}

extern "C" void kernel_launch(void* const* d_in, const int* in_sizes, int n_in,
                              void* d_out, int out_size, void* d_ws, size_t ws_size,
                              hipStream_t stream) {
    const float* x = (const float*)d_in[0];   // [8,512,8,512]
    const float* w = (const float*)d_in[1];   // [8,32000,512]
    const float* b = (const float*)d_in[2];   // [8,32000]
    float* out = (float*)d_out;               // [8,512,32000]

    const size_t xbf_bytes = (size_t)M_DIM * K_DIM * 2;
    const size_t wbf_bytes = (size_t)N_DIM * K_DIM * 2;
    const size_t bs_bytes  = (size_t)N_DIM * 4;
    const size_t need = xbf_bytes + wbf_bytes + bs_bytes;

    if (ws_size < need) {
        long total = (long)M_DIM * N_DIM;
        int blocks = (int)((total + 255) / 256);
        naive_out<<<blocks, 256, 0, stream>>>(x, w, b, out);
        return;
    }

    unsigned short* xbf = (unsigned short*)d_ws;
    unsigned short* wbf = (unsigned short*)((char*)d_ws + xbf_bytes);
    float* bsum = (float*)((char*)d_ws + xbf_bytes + wbf_bytes);

    cvt_x<<<8192, 256, 0, stream>>>(x, xbf);
    cvt_w<<<64000, 256, 0, stream>>>(w, wbf);
    bias_red<<<125, 256, 0, stream>>>(b, bsum);
    gemm256<<<2000, 512, 0, stream>>>(xbf, wbf, bsum, out);  // 16 x 125 tiles
}